// Round 7
// baseline (284.858 us; speedup 1.0000x reference)
//
#include <hip/hip_runtime.h>
#include <stdint.h>

#define AS1 __attribute__((address_space(1)))
#define AS3 __attribute__((address_space(3)))

typedef __bf16 bf16x8 __attribute__((ext_vector_type(8)));
typedef float  f32x4  __attribute__((ext_vector_type(4)));
typedef unsigned short u16x8 __attribute__((ext_vector_type(8)));

static constexpr int NODES  = 50000;
static constexpr int EDGES  = 800000;
static constexpr int INDIM  = 512;
static constexpr int HIDDIM = 256;
static constexpr int NB_SCAN = (NODES + 255) / 256;   // 196
static constexpr int AGG_BLOCKS = NODES / 4;          // 12500 (exact)
static constexpr int RED_BLOCKS = 64;
static constexpr int GEMM_MB = (NODES + 63) / 64;     // 782 row-blocks (BM=64)

// ---------------- ws layout (bytes) ----------------
static constexpr size_t OFF_PART = 0;            // f32  [12500][256]
static constexpr size_t OFF_HN   = 51200000;     // fp8  [50000][256] pre-scaled h (both layers)
static constexpr size_t OFF_H1P  = 76800000;     // bf16 [50000][256] relu(layer1) output
static constexpr size_t OFF_W1T  = 102400000;    // bf16 [256][512]
static constexpr size_t OFF_W2T  = 102662144;    // bf16 [256][256]
static constexpr size_t OFF_DEG  = 102793216;    // i32 [50000]
static constexpr size_t OFF_FILL = 102993216;    // i32 [50000]
static constexpr size_t OFF_ROWP = 103193216;    // i32 [50001]
static constexpr size_t OFF_CSR  = 103393280;    // i32 [800000]
static constexpr size_t OFF_BSUM = 106593280;    // i32 [196]
static constexpr size_t OFF_BOFF = 106594304;    // i32 [256]
static constexpr size_t OFF_FLAG = 106595328;    // i32 (1 => edge_index is int64)
static constexpr size_t OFF_P2   = 106595840;    // f32 [64][256]
static constexpr size_t OFF_DINV = 106661376;    // f32 [50000]

__device__ __forceinline__ unsigned short f2bf(float f) {
  unsigned u = __builtin_bit_cast(unsigned, f);
  unsigned r = (u + 0x7FFFu + ((u >> 16) & 1u)) >> 16;   // RNE
  return (unsigned short)r;
}
__device__ __forceinline__ float bf2f(unsigned short u) {
  return __builtin_bit_cast(float, ((unsigned)u) << 16);
}
__device__ __forceinline__ unsigned char f2fp8(float f) {
  int p = __builtin_amdgcn_cvt_pk_fp8_f32(f, f, 0, false);   // OCP e4m3fn on gfx950
  return (unsigned char)(p & 0xff);
}
__device__ __forceinline__ void acc_fp8(float4& a, unsigned u) {
  a.x += __builtin_amdgcn_cvt_f32_fp8(u, 0);
  a.y += __builtin_amdgcn_cvt_f32_fp8(u, 1);
  a.z += __builtin_amdgcn_cvt_f32_fp8(u, 2);
  a.w += __builtin_amdgcn_cvt_f32_fp8(u, 3);
}
__device__ __forceinline__ void gload_lds16(const unsigned short* g, unsigned short* l) {
  __builtin_amdgcn_global_load_lds((const AS1 void*)g, (AS3 void*)l, 16, 0, 0);
}

// ---------------- edge dtype detect ----------------
__global__ void detect_kernel(const int* __restrict__ ei, int* __restrict__ flag) {
  int t = threadIdx.x;  // 64 threads
  unsigned long long b = __ballot(ei[2 * t + 1] == 0);
  if (t == 0) *flag = (b == 0xFFFFFFFFFFFFFFFFull) ? 1 : 0;
}

// ---------------- degree histogram ----------------
__global__ __launch_bounds__(256) void hist_kernel(const int* __restrict__ ei,
                                                   const int* __restrict__ flag,
                                                   int* __restrict__ deg) {
  int e = blockIdx.x * 256 + threadIdx.x;        // grid exact: 3125*256 = 800000
  int f = *flag;
  int d = f ? ei[2 * (EDGES + e)] : ei[EDGES + e];
  atomicAdd(&deg[d], 1);
}

// ---------------- scan (3 kernels) + dinv ----------------
__global__ __launch_bounds__(256) void scan1_kernel(const int* __restrict__ deg,
                                                    int* __restrict__ rowptr,
                                                    int* __restrict__ bsum,
                                                    float* __restrict__ dinv) {
  __shared__ int s[256];
  int t = threadIdx.x, i = blockIdx.x * 256 + t;
  int v = (i < NODES) ? deg[i] : 0;
  if (i < NODES) dinv[i] = rsqrtf((float)(v + 1));   // +1 self-loop
  s[t] = v; __syncthreads();
  for (int off = 1; off < 256; off <<= 1) {
    int x = (t >= off) ? s[t - off] : 0;
    __syncthreads(); s[t] += x; __syncthreads();
  }
  if (i < NODES) rowptr[i] = s[t] - v;               // block-local exclusive
  if (t == 255) bsum[blockIdx.x] = s[255];
}
__global__ __launch_bounds__(256) void scan2_kernel(const int* __restrict__ bsum,
                                                    int* __restrict__ boff,
                                                    int* __restrict__ rowptrN) {
  __shared__ int s[256];
  int t = threadIdx.x;
  int v = (t < NB_SCAN) ? bsum[t] : 0;
  s[t] = v; __syncthreads();
  for (int off = 1; off < 256; off <<= 1) {
    int x = (t >= off) ? s[t - off] : 0;
    __syncthreads(); s[t] += x; __syncthreads();
  }
  if (t < NB_SCAN) boff[t] = s[t] - v;
  if (t == 255) *rowptrN = s[255];
}
__global__ __launch_bounds__(256) void scan3_kernel(int* __restrict__ rowptr,
                                                    const int* __restrict__ boff) {
  int i = blockIdx.x * 256 + threadIdx.x;
  if (i < NODES) rowptr[i] += boff[blockIdx.x];
}

// ---------------- CSR fill ----------------
__global__ __launch_bounds__(256) void fill_kernel(const int* __restrict__ ei,
                                                   const int* __restrict__ flag,
                                                   const int* __restrict__ rowptr,
                                                   int* __restrict__ fill,
                                                   int* __restrict__ csr) {
  int e = blockIdx.x * 256 + threadIdx.x;
  int f = *flag;
  int s, d;
  if (f) { s = ei[2 * e]; d = ei[2 * (EDGES + e)]; }
  else   { s = ei[e];     d = ei[EDGES + e]; }
  int p = atomicAdd(&fill[d], 1);
  csr[rowptr[d] + p] = s;
}

// ---------------- weight transpose + bf16 ----------------
__global__ __launch_bounds__(256) void transw_kernel(const float* __restrict__ W1,
                                                     const float* __restrict__ W2,
                                                     unsigned short* __restrict__ W1T,
                                                     unsigned short* __restrict__ W2T) {
  int t = blockIdx.x * 256 + threadIdx.x;           // 768*256 = 196608 exact
  if (t < INDIM * HIDDIM) {
    int n = t >> 9, k = t & 511;                    // W1T[n][k] = W1[k][n]
    W1T[t] = f2bf(W1[k * HIDDIM + n]);
  } else {
    int u = t - INDIM * HIDDIM;
    int n = u >> 8, k = u & 255;
    W2T[u] = f2bf(W2[k * HIDDIM + n]);
  }
}

// ---------------- GEMM: BM=64 x BN=256 (full width), BK=32, 2-phase dbuf ----
// A read ONCE (no column-block redundancy); the single B panel (<=256KB) is
// shared by every block -> L2-resident on all XCDs. LDS XOR-swizzled
// (conflict-free, PMC-verified in R5). fp32 A loads lane-contiguous.
// 4 waves (2m x 2n): wave tile 32x128, acc[2][8]. One barrier per K-step.
template<int K, bool AFP32>
__global__ __launch_bounds__(256) void gemm_n256_kernel(const void* __restrict__ Av,
                                                        const unsigned short* __restrict__ BT,
                                                        const float* __restrict__ dinv,
                                                        unsigned char* __restrict__ Cn8) {
  constexpr int NSTEP = K / 32;
  __shared__ unsigned short As[2][64 * 32];    // 4 KB per buf
  __shared__ unsigned short Bs[2][256 * 32];   // 16 KB per buf  (total 40 KB)
  const int tid = threadIdx.x, wave = tid >> 6, lane = tid & 63;
  const int fr = lane & 15, q = lane >> 4;
  const int wr = wave >> 1, wc = wave & 1;
  const int m0 = blockIdx.x * 64;

  const int lrow4 = lane >> 2;                 // 0..15: row within 16-row chunk
  const int sgq   = (lane & 3) ^ (lrow4 & 3);  // pre-swizzled source group (16B)
  const unsigned short* a16 = (const unsigned short*)Av;
  const float*          a32 = (const float*)Av;

  f32x4 acc[2][8] = {};
  float4 fa0, fa1;                             // fp32 A staging regs

#define STAGE_B(buf, kb)                                                      \
  {                                                                           \
    _Pragma("unroll")                                                         \
    for (int c = 0; c < 4; ++c) {                                             \
      int i = wave * 4 + c;                     /* 16-row chunk 0..15 */      \
      int gr = i * 16 + lrow4;                                                \
      gload_lds16(BT + (size_t)gr * K + (kb) + sgq * 8, &Bs[buf][i * 512]);   \
    }                                                                         \
  }
#define STAGE_A16(buf, kb)                                                    \
  {                                                                           \
    int gr = m0 + wave * 16 + lrow4; if (gr > NODES - 1) gr = NODES - 1;      \
    gload_lds16(a16 + (size_t)gr * K + (kb) + sgq * 8, &As[buf][wave * 512]); \
  }
#define LOAD_A32(kb)                                                          \
  {                                                                           \
    int F0 = tid, F1 = tid + 256;              /* lane-contiguous float4 */   \
    int r0 = m0 + (F0 >> 3); if (r0 > NODES - 1) r0 = NODES - 1;              \
    int r1 = m0 + (F1 >> 3); if (r1 > NODES - 1) r1 = NODES - 1;              \
    fa0 = *(const float4*)(a32 + (size_t)r0 * K + (kb) + (F0 & 7) * 4);       \
    fa1 = *(const float4*)(a32 + (size_t)r1 * K + (kb) + (F1 & 7) * 4);       \
  }
#define WRITE_A32(buf)                                                        \
  {                                                                           \
    _Pragma("unroll")                                                         \
    for (int j = 0; j < 2; ++j) {                                             \
      int F = tid + j * 256;                                                  \
      int row = F >> 3, g4 = F & 7;                                           \
      float4 v = j ? fa1 : fa0;                                               \
      ushort4 o{f2bf(v.x), f2bf(v.y), f2bf(v.z), f2bf(v.w)};                  \
      int col = (((g4 >> 1) ^ (row & 3)) * 8) + (g4 & 1) * 4;                 \
      *(ushort4*)&As[buf][row * 32 + col] = o;                                \
    }                                                                         \
  }

  // ---- prologue: stage step 0 into buf 0 ----
  if constexpr (AFP32) { LOAD_A32(0); WRITE_A32(0); }
  else                 { STAGE_A16(0, 0); }
  STAGE_B(0, 0);
  __syncthreads();

  for (int t = 0; t < NSTEP; ++t) {
    const int cur = t & 1, nxt = cur ^ 1;
    const int kb1 = (t + 1) * 32;
    if (t + 1 < NSTEP) {                        // issue next-tile loads first
      if constexpr (AFP32) { LOAD_A32(kb1); }
      else                 { STAGE_A16(nxt, kb1); }
      STAGE_B(nxt, kb1);
    }
    bf16x8 af[2], bq[8];
#pragma unroll
    for (int m = 0; m < 2; ++m) {
      int row = wr * 32 + m * 16 + fr;
      af[m] = *(const bf16x8*)&As[cur][row * 32 + ((q ^ (row & 3)) * 8)];
    }
#pragma unroll
    for (int n = 0; n < 8; ++n) {
      int row = wc * 128 + n * 16 + fr;
      bq[n] = *(const bf16x8*)&Bs[cur][row * 32 + ((q ^ (row & 3)) * 8)];
    }
#pragma unroll
    for (int m = 0; m < 2; ++m)
#pragma unroll
      for (int n = 0; n < 8; ++n)
        acc[m][n] = __builtin_amdgcn_mfma_f32_16x16x32_bf16(af[m], bq[n], acc[m][n], 0, 0, 0);
    if (t + 1 < NSTEP) {
      if constexpr (AFP32) { WRITE_A32(nxt); }  // land A prefetch after MFMAs
    }
    __syncthreads();
  }
#undef STAGE_B
#undef STAGE_A16
#undef LOAD_A32
#undef WRITE_A32

  // epilogue: C/D layout col=lane&15, row=q*4+reg ; write fp8 with dinv scale
  const int rq = q * 4;
#pragma unroll
  for (int m = 0; m < 2; ++m) {
    int rbase = m0 + wr * 32 + m * 16 + rq;
#pragma unroll
    for (int r = 0; r < 4; ++r) {
      int grow = rbase + r;
      if (grow < NODES) {
        float dv = dinv[grow];
#pragma unroll
        for (int n = 0; n < 8; ++n) {
          int gcol = wc * 128 + n * 16 + fr;
          Cn8[(size_t)grow * 256 + gcol] = f2fp8(acc[m][n][r] * dv);
        }
      }
    }
  }
}

// ---------------- gather core: fp8 rows, unroll-8 (8 rows in flight) ----------------
__device__ __forceinline__ float4 gather_node(const unsigned char* __restrict__ hn8,
                                              const int* __restrict__ rowptr,
                                              const int* __restrict__ csr,
                                              int node, int boff) {
  float4 A{0.f, 0.f, 0.f, 0.f}, B{0.f, 0.f, 0.f, 0.f};
  unsigned us = *(const unsigned*)(hn8 + (size_t)node * 256 + boff);   // self-loop
  acc_fp8(A, us);
  int e0 = rowptr[node], e1 = rowptr[node + 1];
  int e = e0;
  for (; e + 8 <= e1; e += 8) {
    unsigned u0 = *(const unsigned*)(hn8 + (size_t)csr[e + 0] * 256 + boff);
    unsigned u1 = *(const unsigned*)(hn8 + (size_t)csr[e + 1] * 256 + boff);
    unsigned u2 = *(const unsigned*)(hn8 + (size_t)csr[e + 2] * 256 + boff);
    unsigned u3 = *(const unsigned*)(hn8 + (size_t)csr[e + 3] * 256 + boff);
    unsigned u4 = *(const unsigned*)(hn8 + (size_t)csr[e + 4] * 256 + boff);
    unsigned u5 = *(const unsigned*)(hn8 + (size_t)csr[e + 5] * 256 + boff);
    unsigned u6 = *(const unsigned*)(hn8 + (size_t)csr[e + 6] * 256 + boff);
    unsigned u7 = *(const unsigned*)(hn8 + (size_t)csr[e + 7] * 256 + boff);
    acc_fp8(A, u0); acc_fp8(B, u1); acc_fp8(A, u2); acc_fp8(B, u3);
    acc_fp8(A, u4); acc_fp8(B, u5); acc_fp8(A, u6); acc_fp8(B, u7);
  }
  for (; e + 4 <= e1; e += 4) {
    unsigned u0 = *(const unsigned*)(hn8 + (size_t)csr[e + 0] * 256 + boff);
    unsigned u1 = *(const unsigned*)(hn8 + (size_t)csr[e + 1] * 256 + boff);
    unsigned u2 = *(const unsigned*)(hn8 + (size_t)csr[e + 2] * 256 + boff);
    unsigned u3 = *(const unsigned*)(hn8 + (size_t)csr[e + 3] * 256 + boff);
    acc_fp8(A, u0); acc_fp8(B, u1); acc_fp8(A, u2); acc_fp8(B, u3);
  }
  for (; e < e1; ++e) {
    unsigned u = *(const unsigned*)(hn8 + (size_t)csr[e] * 256 + boff);
    acc_fp8(A, u);
  }
  return float4{A.x + B.x, A.y + B.y, A.z + B.z, A.w + B.w};
}

// ---------------- aggregation: wave per node, CSR gather ----------------
__global__ __launch_bounds__(256) void agg1_kernel(const unsigned char* __restrict__ hn8,
                                                   const float* __restrict__ dinv,
                                                   const int* __restrict__ rowptr,
                                                   const int* __restrict__ csr,
                                                   const float* __restrict__ bias,
                                                   unsigned short* __restrict__ outp) {
  int wave = threadIdx.x >> 6, lane = threadIdx.x & 63;
  int node = blockIdx.x * 4 + wave;
  int c0 = lane * 4;
  float4 a = gather_node(hn8, rowptr, csr, node, c0);
  float di = dinv[node];
  float4 b = *(const float4*)(bias + c0);
  ushort4 o{f2bf(fmaxf(fmaf(di, a.x, b.x), 0.f)),
            f2bf(fmaxf(fmaf(di, a.y, b.y), 0.f)),
            f2bf(fmaxf(fmaf(di, a.z, b.z), 0.f)),
            f2bf(fmaxf(fmaf(di, a.w, b.w), 0.f))};
  *(ushort4*)(outp + (size_t)node * 256 + c0) = o;
}

__global__ __launch_bounds__(256) void agg2_kernel(const unsigned char* __restrict__ hn8,
                                                   const float* __restrict__ dinv,
                                                   const int* __restrict__ rowptr,
                                                   const int* __restrict__ csr,
                                                   const float* __restrict__ bias,
                                                   float* __restrict__ partials) {
  __shared__ float sm[1024];
  int wave = threadIdx.x >> 6, lane = threadIdx.x & 63;
  int node = blockIdx.x * 4 + wave;                 // 12500*4 = 50000 exact
  int c0 = lane * 4;
  float4 a = gather_node(hn8, rowptr, csr, node, c0);
  float di = dinv[node];
  float4 b = *(const float4*)(bias + c0);
  sm[wave * 256 + c0 + 0] = fmaxf(fmaf(di, a.x, b.x), 0.f);
  sm[wave * 256 + c0 + 1] = fmaxf(fmaf(di, a.y, b.y), 0.f);
  sm[wave * 256 + c0 + 2] = fmaxf(fmaf(di, a.z, b.z), 0.f);
  sm[wave * 256 + c0 + 3] = fmaxf(fmaf(di, a.w, b.w), 0.f);
  __syncthreads();
  int t = threadIdx.x;
  partials[(size_t)blockIdx.x * 256 + t] = sm[t] + sm[256 + t] + sm[512 + t] + sm[768 + t];
}

// ---------------- readout ----------------
__global__ __launch_bounds__(256) void reduce2_kernel(const float* __restrict__ partials,
                                                      float* __restrict__ p2) {
  int t = threadIdx.x, b = blockIdx.x;              // 64 blocks
  float s = 0.f;
  for (int r = b; r < AGG_BLOCKS; r += RED_BLOCKS) s += partials[(size_t)r * 256 + t];
  p2[b * 256 + t] = s;
}
__global__ __launch_bounds__(256) void final_kernel(const float* __restrict__ p2,
                                                    const float* __restrict__ Wfc,
                                                    const float* __restrict__ bfc,
                                                    float* __restrict__ out) {
  __shared__ float red[256];
  int t = threadIdx.x;
  float s = 0.f;
  for (int b = 0; b < RED_BLOCKS; ++b) s += p2[b * 256 + t];
  float g = s * (1.0f / (float)NODES);
  red[t] = g * Wfc[t];
  __syncthreads();
  for (int off = 128; off > 0; off >>= 1) {
    if (t < off) red[t] += red[t + off];
    __syncthreads();
  }
  if (t == 0) {
    float z = red[0] + bfc[0];
    out[0] = 1.0f / (1.0f + expf(-z));
  }
}

// ---------------- launch ----------------
extern "C" void kernel_launch(void* const* d_in, const int* in_sizes, int n_in,
                              void* d_out, int out_size, void* d_ws, size_t ws_size,
                              hipStream_t stream) {
  (void)in_sizes; (void)n_in; (void)out_size; (void)ws_size;
  const float* x   = (const float*)d_in[0];
  const int*   ei  = (const int*)d_in[1];
  const float* W1  = (const float*)d_in[2];
  const float* b1  = (const float*)d_in[3];
  const float* W2  = (const float*)d_in[4];
  const float* b2  = (const float*)d_in[5];
  const float* Wfc = (const float*)d_in[6];
  const float* bfc = (const float*)d_in[7];
  float* out = (float*)d_out;
  char* ws = (char*)d_ws;

  unsigned char*  hn8  = (unsigned char*)(ws + OFF_HN);
  unsigned short* h1p  = (unsigned short*)(ws + OFF_H1P);
  unsigned short* w1t  = (unsigned short*)(ws + OFF_W1T);
  unsigned short* w2t  = (unsigned short*)(ws + OFF_W2T);
  int*   deg    = (int*)(ws + OFF_DEG);
  int*   fill   = (int*)(ws + OFF_FILL);
  int*   rowptr = (int*)(ws + OFF_ROWP);
  int*   csr    = (int*)(ws + OFF_CSR);
  int*   bsum   = (int*)(ws + OFF_BSUM);
  int*   boff   = (int*)(ws + OFF_BOFF);
  int*   flag   = (int*)(ws + OFF_FLAG);
  float* part   = (float*)(ws + OFF_PART);
  float* p2     = (float*)(ws + OFF_P2);
  float* dinv   = (float*)(ws + OFF_DINV);

  hipMemsetAsync(ws + OFF_DEG, 0, 400000, stream);  // deg + fill
  detect_kernel<<<1, 64, 0, stream>>>(ei, flag);
  hist_kernel<<<EDGES / 256, 256, 0, stream>>>(ei, flag, deg);
  scan1_kernel<<<NB_SCAN, 256, 0, stream>>>(deg, rowptr, bsum, dinv);
  scan2_kernel<<<1, 256, 0, stream>>>(bsum, boff, rowptr + NODES);
  scan3_kernel<<<NB_SCAN, 256, 0, stream>>>(rowptr, boff);
  fill_kernel<<<EDGES / 256, 256, 0, stream>>>(ei, flag, rowptr, fill, csr);

  transw_kernel<<<(INDIM * HIDDIM + HIDDIM * HIDDIM) / 256, 256, 0, stream>>>(W1, W2, w1t, w2t);

  gemm_n256_kernel<INDIM, true><<<GEMM_MB, 256, 0, stream>>>(x, w1t, dinv, hn8);
  agg1_kernel<<<AGG_BLOCKS, 256, 0, stream>>>(hn8, dinv, rowptr, csr, b1, h1p);
  gemm_n256_kernel<HIDDIM, false><<<GEMM_MB, 256, 0, stream>>>(h1p, w2t, dinv, hn8);
  agg2_kernel<<<AGG_BLOCKS, 256, 0, stream>>>(hn8, dinv, rowptr, csr, b2, part);
  reduce2_kernel<<<RED_BLOCKS, 256, 0, stream>>>(part, p2);
  final_kernel<<<1, 256, 0, stream>>>(p2, Wfc, bfc, out);
}

// Round 8
// 281.514 us; speedup vs baseline: 1.0119x; 1.0119x over previous
//
#include <hip/hip_runtime.h>
#include <stdint.h>

#define AS1 __attribute__((address_space(1)))
#define AS3 __attribute__((address_space(3)))

typedef __bf16 bf16x8 __attribute__((ext_vector_type(8)));
typedef float  f32x4  __attribute__((ext_vector_type(4)));
typedef unsigned short u16x8 __attribute__((ext_vector_type(8)));

static constexpr int NODES  = 50000;
static constexpr int EDGES  = 800000;
static constexpr int INDIM  = 512;
static constexpr int HIDDIM = 256;
static constexpr int NB_SCAN = (NODES + 255) / 256;   // 196
static constexpr int AGG_BLOCKS = NODES / 4;          // 12500 (exact)
static constexpr int RED_BLOCKS = 64;
static constexpr int GEMM_MB = (NODES + 63) / 64;     // 782 row-blocks (BM=64)

// ---------------- ws layout (bytes) ----------------
static constexpr size_t OFF_PART = 0;            // f32  [12500][256]
static constexpr size_t OFF_HN   = 51200000;     // fp8  [50000][256] pre-scaled h (both layers)
static constexpr size_t OFF_H1P  = 76800000;     // bf16 [50000][256] relu(layer1) output
static constexpr size_t OFF_W1T  = 102400000;    // bf16 [256][512]
static constexpr size_t OFF_W2T  = 102662144;    // bf16 [256][256]
static constexpr size_t OFF_DEG  = 102793216;    // i32 [50000]
static constexpr size_t OFF_FILL = 102993216;    // i32 [50000]
static constexpr size_t OFF_ROWP = 103193216;    // i32 [50001]
static constexpr size_t OFF_CSR  = 103393280;    // i32 [800000]
static constexpr size_t OFF_BSUM = 106593280;    // i32 [196]
static constexpr size_t OFF_BOFF = 106594304;    // i32 [256]
static constexpr size_t OFF_FLAG = 106595328;    // i32 (1 => edge_index is int64)
static constexpr size_t OFF_P2   = 106595840;    // f32 [64][256]
static constexpr size_t OFF_DINV = 106661376;    // f32 [50000]

__device__ __forceinline__ unsigned short f2bf(float f) {
  unsigned u = __builtin_bit_cast(unsigned, f);
  unsigned r = (u + 0x7FFFu + ((u >> 16) & 1u)) >> 16;   // RNE
  return (unsigned short)r;
}
__device__ __forceinline__ float bf2f(unsigned short u) {
  return __builtin_bit_cast(float, ((unsigned)u) << 16);
}
__device__ __forceinline__ unsigned char f2fp8(float f) {
  int p = __builtin_amdgcn_cvt_pk_fp8_f32(f, f, 0, false);   // OCP e4m3fn on gfx950
  return (unsigned char)(p & 0xff);
}
__device__ __forceinline__ void acc_fp8(float4& a, unsigned u) {
  a.x += __builtin_amdgcn_cvt_f32_fp8(u, 0);
  a.y += __builtin_amdgcn_cvt_f32_fp8(u, 1);
  a.z += __builtin_amdgcn_cvt_f32_fp8(u, 2);
  a.w += __builtin_amdgcn_cvt_f32_fp8(u, 3);
}
__device__ __forceinline__ void gload_lds16(const unsigned short* g, unsigned short* l) {
  __builtin_amdgcn_global_load_lds((const AS1 void*)g, (AS3 void*)l, 16, 0, 0);
}

// ---------------- edge dtype detect ----------------
__global__ void detect_kernel(const int* __restrict__ ei, int* __restrict__ flag) {
  int t = threadIdx.x;  // 64 threads
  unsigned long long b = __ballot(ei[2 * t + 1] == 0);
  if (t == 0) *flag = (b == 0xFFFFFFFFFFFFFFFFull) ? 1 : 0;
}

// ---------------- degree histogram ----------------
__global__ __launch_bounds__(256) void hist_kernel(const int* __restrict__ ei,
                                                   const int* __restrict__ flag,
                                                   int* __restrict__ deg) {
  int e = blockIdx.x * 256 + threadIdx.x;        // grid exact: 3125*256 = 800000
  int f = *flag;
  int d = f ? ei[2 * (EDGES + e)] : ei[EDGES + e];
  atomicAdd(&deg[d], 1);
}

// ---------------- scan (3 kernels) + dinv ----------------
__global__ __launch_bounds__(256) void scan1_kernel(const int* __restrict__ deg,
                                                    int* __restrict__ rowptr,
                                                    int* __restrict__ bsum,
                                                    float* __restrict__ dinv) {
  __shared__ int s[256];
  int t = threadIdx.x, i = blockIdx.x * 256 + t;
  int v = (i < NODES) ? deg[i] : 0;
  if (i < NODES) dinv[i] = rsqrtf((float)(v + 1));   // +1 self-loop
  s[t] = v; __syncthreads();
  for (int off = 1; off < 256; off <<= 1) {
    int x = (t >= off) ? s[t - off] : 0;
    __syncthreads(); s[t] += x; __syncthreads();
  }
  if (i < NODES) rowptr[i] = s[t] - v;               // block-local exclusive
  if (t == 255) bsum[blockIdx.x] = s[255];
}
__global__ __launch_bounds__(256) void scan2_kernel(const int* __restrict__ bsum,
                                                    int* __restrict__ boff,
                                                    int* __restrict__ rowptrN) {
  __shared__ int s[256];
  int t = threadIdx.x;
  int v = (t < NB_SCAN) ? bsum[t] : 0;
  s[t] = v; __syncthreads();
  for (int off = 1; off < 256; off <<= 1) {
    int x = (t >= off) ? s[t - off] : 0;
    __syncthreads(); s[t] += x; __syncthreads();
  }
  if (t < NB_SCAN) boff[t] = s[t] - v;
  if (t == 255) *rowptrN = s[255];
}
__global__ __launch_bounds__(256) void scan3_kernel(int* __restrict__ rowptr,
                                                    const int* __restrict__ boff) {
  int i = blockIdx.x * 256 + threadIdx.x;
  if (i < NODES) rowptr[i] += boff[blockIdx.x];
}

// ---------------- CSR fill ----------------
__global__ __launch_bounds__(256) void fill_kernel(const int* __restrict__ ei,
                                                   const int* __restrict__ flag,
                                                   const int* __restrict__ rowptr,
                                                   int* __restrict__ fill,
                                                   int* __restrict__ csr) {
  int e = blockIdx.x * 256 + threadIdx.x;
  int f = *flag;
  int s, d;
  if (f) { s = ei[2 * e]; d = ei[2 * (EDGES + e)]; }
  else   { s = ei[e];     d = ei[EDGES + e]; }
  int p = atomicAdd(&fill[d], 1);
  csr[rowptr[d] + p] = s;
}

// ---------------- weight transpose + bf16 ----------------
__global__ __launch_bounds__(256) void transw_kernel(const float* __restrict__ W1,
                                                     const float* __restrict__ W2,
                                                     unsigned short* __restrict__ W1T,
                                                     unsigned short* __restrict__ W2T) {
  int t = blockIdx.x * 256 + threadIdx.x;           // 768*256 = 196608 exact
  if (t < INDIM * HIDDIM) {
    int n = t >> 9, k = t & 511;                    // W1T[n][k] = W1[k][n]
    W1T[t] = f2bf(W1[k * HIDDIM + n]);
  } else {
    int u = t - INDIM * HIDDIM;
    int n = u >> 8, k = u & 255;
    W2T[u] = f2bf(W2[k * HIDDIM + n]);
  }
}

// ---------------- GEMM: BM=64 x BN=256, BK=32 dbuf, 512 threads / 8 waves ----
// Same tile as R6 but 8 waves (2m x 4n, wave tile 32x64): per-thread staging
// halves and resident waves/CU ~double -> TLP hides the vmcnt(0)+barrier
// drain that capped R1-R6 at ~60us. LDS 40KB (<=4 blocks/CU by LDS; ~2 by
// VGPR). One barrier per K-step; fp32-A reg-staged (load early, write late).
template<int K, bool AFP32>
__global__ __launch_bounds__(512, 4) void gemm_n256_kernel(const void* __restrict__ Av,
                                                           const unsigned short* __restrict__ BT,
                                                           const float* __restrict__ dinv,
                                                           unsigned char* __restrict__ Cn8) {
  constexpr int NSTEP = K / 32;
  __shared__ unsigned short As[2][64 * 32];    // 4 KB per buf
  __shared__ unsigned short Bs[2][256 * 32];   // 16 KB per buf  (total 40 KB)
  const int tid = threadIdx.x, wave = tid >> 6, lane = tid & 63;
  const int fr = lane & 15, q = lane >> 4;
  const int wr = wave >> 2, wc = wave & 3;     // 2m x 4n
  const int m0 = blockIdx.x * 64;

  const int lrow4 = lane >> 2;                 // 0..15: row within 16-row slab
  const int sgq   = (lane & 3) ^ (lrow4 & 3);  // pre-swizzled source 16B group
  const unsigned short* a16 = (const unsigned short*)Av;
  const float*          a32 = (const float*)Av;

  f32x4 acc[2][4] = {};
  float4 fa;                                   // fp32 A staging reg (1/thread)

  // B: 256 rows x 32 cols = 1024 x16B chunks; 2 slabs of 128 rows; thread's
  // wave covers 16 rows/slab, lane>>2 = row-in-slab, lane&3 = 16B group.
#define STAGE_B(buf, kb)                                                      \
  {                                                                           \
    _Pragma("unroll")                                                         \
    for (int j = 0; j < 2; ++j) {                                             \
      int rbase = j * 128 + wave * 16;                                        \
      int gr = rbase + lrow4;                                                 \
      gload_lds16(BT + (size_t)gr * K + (kb) + sgq * 8,                       \
                  &Bs[buf][rbase * 32]);                                      \
    }                                                                         \
  }
  // A bf16 (gemm2): 64 rows x 4 chunks = 256 chunks; waves 0-3 only.
#define STAGE_A16(buf, kb)                                                    \
  {                                                                           \
    if (wave < 4) {                                                           \
      int rbase = wave * 16;                                                  \
      int gr = m0 + rbase + lrow4; if (gr > NODES - 1) gr = NODES - 1;        \
      gload_lds16(a16 + (size_t)gr * K + (kb) + sgq * 8,                      \
                  &As[buf][rbase * 32]);                                      \
    }                                                                         \
  }
  // A fp32: 64 rows x 8 float4; thread -> (row=tid>>3, g4=tid&7). Lane-contig.
#define LOAD_A32(kb)                                                          \
  {                                                                           \
    int r0 = m0 + (tid >> 3); if (r0 > NODES - 1) r0 = NODES - 1;             \
    fa = *(const float4*)(a32 + (size_t)r0 * K + (kb) + (tid & 7) * 4);       \
  }
#define WRITE_A32(buf)                                                        \
  {                                                                           \
    int row = tid >> 3, g4 = tid & 7;                                         \
    ushort4 o{f2bf(fa.x), f2bf(fa.y), f2bf(fa.z), f2bf(fa.w)};                \
    int col = (((g4 >> 1) ^ (row & 3)) * 8) + (g4 & 1) * 4;                   \
    *(ushort4*)&As[buf][row * 32 + col] = o;                                  \
  }

  // ---- prologue: stage step 0 into buf 0 ----
  if constexpr (AFP32) { LOAD_A32(0); WRITE_A32(0); }
  else                 { STAGE_A16(0, 0); }
  STAGE_B(0, 0);
  __syncthreads();

  for (int t = 0; t < NSTEP; ++t) {
    const int cur = t & 1, nxt = cur ^ 1;
    const int kb1 = (t + 1) * 32;
    if (t + 1 < NSTEP) {                        // issue next-tile loads first
      if constexpr (AFP32) { LOAD_A32(kb1); }
      else                 { STAGE_A16(nxt, kb1); }
      STAGE_B(nxt, kb1);
    }
    bf16x8 af[2], bq[4];
#pragma unroll
    for (int m = 0; m < 2; ++m) {
      int row = wr * 32 + m * 16 + fr;
      af[m] = *(const bf16x8*)&As[cur][row * 32 + ((q ^ (row & 3)) * 8)];
    }
#pragma unroll
    for (int n = 0; n < 4; ++n) {
      int row = wc * 64 + n * 16 + fr;
      bq[n] = *(const bf16x8*)&Bs[cur][row * 32 + ((q ^ (row & 3)) * 8)];
    }
#pragma unroll
    for (int m = 0; m < 2; ++m)
#pragma unroll
      for (int n = 0; n < 4; ++n)
        acc[m][n] = __builtin_amdgcn_mfma_f32_16x16x32_bf16(af[m], bq[n], acc[m][n], 0, 0, 0);
    if (t + 1 < NSTEP) {
      if constexpr (AFP32) { WRITE_A32(nxt); }  // land A prefetch after MFMAs
    }
    __syncthreads();
  }
#undef STAGE_B
#undef STAGE_A16
#undef LOAD_A32
#undef WRITE_A32

  // epilogue: C/D layout col=lane&15, row=q*4+reg ; write fp8 with dinv scale
  const int rq = q * 4;
#pragma unroll
  for (int m = 0; m < 2; ++m) {
    int rbase = m0 + wr * 32 + m * 16 + rq;
#pragma unroll
    for (int r = 0; r < 4; ++r) {
      int grow = rbase + r;
      if (grow < NODES) {
        float dv = dinv[grow];
#pragma unroll
        for (int n = 0; n < 4; ++n) {
          int gcol = wc * 64 + n * 16 + fr;
          Cn8[(size_t)grow * 256 + gcol] = f2fp8(acc[m][n][r] * dv);
        }
      }
    }
  }
}

// ---------------- gather core: fp8 rows, unroll-8 (8 rows in flight) ----------------
__device__ __forceinline__ float4 gather_node(const unsigned char* __restrict__ hn8,
                                              const int* __restrict__ rowptr,
                                              const int* __restrict__ csr,
                                              int node, int boff) {
  float4 A{0.f, 0.f, 0.f, 0.f}, B{0.f, 0.f, 0.f, 0.f};
  unsigned us = *(const unsigned*)(hn8 + (size_t)node * 256 + boff);   // self-loop
  acc_fp8(A, us);
  int e0 = rowptr[node], e1 = rowptr[node + 1];
  int e = e0;
  for (; e + 8 <= e1; e += 8) {
    unsigned u0 = *(const unsigned*)(hn8 + (size_t)csr[e + 0] * 256 + boff);
    unsigned u1 = *(const unsigned*)(hn8 + (size_t)csr[e + 1] * 256 + boff);
    unsigned u2 = *(const unsigned*)(hn8 + (size_t)csr[e + 2] * 256 + boff);
    unsigned u3 = *(const unsigned*)(hn8 + (size_t)csr[e + 3] * 256 + boff);
    unsigned u4 = *(const unsigned*)(hn8 + (size_t)csr[e + 4] * 256 + boff);
    unsigned u5 = *(const unsigned*)(hn8 + (size_t)csr[e + 5] * 256 + boff);
    unsigned u6 = *(const unsigned*)(hn8 + (size_t)csr[e + 6] * 256 + boff);
    unsigned u7 = *(const unsigned*)(hn8 + (size_t)csr[e + 7] * 256 + boff);
    acc_fp8(A, u0); acc_fp8(B, u1); acc_fp8(A, u2); acc_fp8(B, u3);
    acc_fp8(A, u4); acc_fp8(B, u5); acc_fp8(A, u6); acc_fp8(B, u7);
  }
  for (; e + 4 <= e1; e += 4) {
    unsigned u0 = *(const unsigned*)(hn8 + (size_t)csr[e + 0] * 256 + boff);
    unsigned u1 = *(const unsigned*)(hn8 + (size_t)csr[e + 1] * 256 + boff);
    unsigned u2 = *(const unsigned*)(hn8 + (size_t)csr[e + 2] * 256 + boff);
    unsigned u3 = *(const unsigned*)(hn8 + (size_t)csr[e + 3] * 256 + boff);
    acc_fp8(A, u0); acc_fp8(B, u1); acc_fp8(A, u2); acc_fp8(B, u3);
  }
  for (; e < e1; ++e) {
    unsigned u = *(const unsigned*)(hn8 + (size_t)csr[e] * 256 + boff);
    acc_fp8(A, u);
  }
  return float4{A.x + B.x, A.y + B.y, A.z + B.z, A.w + B.w};
}

// ---------------- aggregation: wave per node, CSR gather ----------------
__global__ __launch_bounds__(256) void agg1_kernel(const unsigned char* __restrict__ hn8,
                                                   const float* __restrict__ dinv,
                                                   const int* __restrict__ rowptr,
                                                   const int* __restrict__ csr,
                                                   const float* __restrict__ bias,
                                                   unsigned short* __restrict__ outp) {
  int wave = threadIdx.x >> 6, lane = threadIdx.x & 63;
  int node = blockIdx.x * 4 + wave;
  int c0 = lane * 4;
  float4 a = gather_node(hn8, rowptr, csr, node, c0);
  float di = dinv[node];
  float4 b = *(const float4*)(bias + c0);
  ushort4 o{f2bf(fmaxf(fmaf(di, a.x, b.x), 0.f)),
            f2bf(fmaxf(fmaf(di, a.y, b.y), 0.f)),
            f2bf(fmaxf(fmaf(di, a.z, b.z), 0.f)),
            f2bf(fmaxf(fmaf(di, a.w, b.w), 0.f))};
  *(ushort4*)(outp + (size_t)node * 256 + c0) = o;
}

__global__ __launch_bounds__(256) void agg2_kernel(const unsigned char* __restrict__ hn8,
                                                   const float* __restrict__ dinv,
                                                   const int* __restrict__ rowptr,
                                                   const int* __restrict__ csr,
                                                   const float* __restrict__ bias,
                                                   float* __restrict__ partials) {
  __shared__ float sm[1024];
  int wave = threadIdx.x >> 6, lane = threadIdx.x & 63;
  int node = blockIdx.x * 4 + wave;                 // 12500*4 = 50000 exact
  int c0 = lane * 4;
  float4 a = gather_node(hn8, rowptr, csr, node, c0);
  float di = dinv[node];
  float4 b = *(const float4*)(bias + c0);
  sm[wave * 256 + c0 + 0] = fmaxf(fmaf(di, a.x, b.x), 0.f);
  sm[wave * 256 + c0 + 1] = fmaxf(fmaf(di, a.y, b.y), 0.f);
  sm[wave * 256 + c0 + 2] = fmaxf(fmaf(di, a.z, b.z), 0.f);
  sm[wave * 256 + c0 + 3] = fmaxf(fmaf(di, a.w, b.w), 0.f);
  __syncthreads();
  int t = threadIdx.x;
  partials[(size_t)blockIdx.x * 256 + t] = sm[t] + sm[256 + t] + sm[512 + t] + sm[768 + t];
}

// ---------------- readout ----------------
__global__ __launch_bounds__(256) void reduce2_kernel(const float* __restrict__ partials,
                                                      float* __restrict__ p2) {
  int t = threadIdx.x, b = blockIdx.x;              // 64 blocks
  float s = 0.f;
  for (int r = b; r < AGG_BLOCKS; r += RED_BLOCKS) s += partials[(size_t)r * 256 + t];
  p2[b * 256 + t] = s;
}
__global__ __launch_bounds__(256) void final_kernel(const float* __restrict__ p2,
                                                    const float* __restrict__ Wfc,
                                                    const float* __restrict__ bfc,
                                                    float* __restrict__ out) {
  __shared__ float red[256];
  int t = threadIdx.x;
  float s = 0.f;
  for (int b = 0; b < RED_BLOCKS; ++b) s += p2[b * 256 + t];
  float g = s * (1.0f / (float)NODES);
  red[t] = g * Wfc[t];
  __syncthreads();
  for (int off = 128; off > 0; off >>= 1) {
    if (t < off) red[t] += red[t + off];
    __syncthreads();
  }
  if (t == 0) {
    float z = red[0] + bfc[0];
    out[0] = 1.0f / (1.0f + expf(-z));
  }
}

// ---------------- launch ----------------
extern "C" void kernel_launch(void* const* d_in, const int* in_sizes, int n_in,
                              void* d_out, int out_size, void* d_ws, size_t ws_size,
                              hipStream_t stream) {
  (void)in_sizes; (void)n_in; (void)out_size; (void)ws_size;
  const float* x   = (const float*)d_in[0];
  const int*   ei  = (const int*)d_in[1];
  const float* W1  = (const float*)d_in[2];
  const float* b1  = (const float*)d_in[3];
  const float* W2  = (const float*)d_in[4];
  const float* b2  = (const float*)d_in[5];
  const float* Wfc = (const float*)d_in[6];
  const float* bfc = (const float*)d_in[7];
  float* out = (float*)d_out;
  char* ws = (char*)d_ws;

  unsigned char*  hn8  = (unsigned char*)(ws + OFF_HN);
  unsigned short* h1p  = (unsigned short*)(ws + OFF_H1P);
  unsigned short* w1t  = (unsigned short*)(ws + OFF_W1T);
  unsigned short* w2t  = (unsigned short*)(ws + OFF_W2T);
  int*   deg    = (int*)(ws + OFF_DEG);
  int*   fill   = (int*)(ws + OFF_FILL);
  int*   rowptr = (int*)(ws + OFF_ROWP);
  int*   csr    = (int*)(ws + OFF_CSR);
  int*   bsum   = (int*)(ws + OFF_BSUM);
  int*   boff   = (int*)(ws + OFF_BOFF);
  int*   flag   = (int*)(ws + OFF_FLAG);
  float* part   = (float*)(ws + OFF_PART);
  float* p2     = (float*)(ws + OFF_P2);
  float* dinv   = (float*)(ws + OFF_DINV);

  hipMemsetAsync(ws + OFF_DEG, 0, 400000, stream);  // deg + fill
  detect_kernel<<<1, 64, 0, stream>>>(ei, flag);
  hist_kernel<<<EDGES / 256, 256, 0, stream>>>(ei, flag, deg);
  scan1_kernel<<<NB_SCAN, 256, 0, stream>>>(deg, rowptr, bsum, dinv);
  scan2_kernel<<<1, 256, 0, stream>>>(bsum, boff, rowptr + NODES);
  scan3_kernel<<<NB_SCAN, 256, 0, stream>>>(rowptr, boff);
  fill_kernel<<<EDGES / 256, 256, 0, stream>>>(ei, flag, rowptr, fill, csr);

  transw_kernel<<<(INDIM * HIDDIM + HIDDIM * HIDDIM) / 256, 256, 0, stream>>>(W1, W2, w1t, w2t);

  gemm_n256_kernel<INDIM, true><<<GEMM_MB, 512, 0, stream>>>(x, w1t, dinv, hn8);
  agg1_kernel<<<AGG_BLOCKS, 256, 0, stream>>>(hn8, dinv, rowptr, csr, b1, h1p);
  gemm_n256_kernel<HIDDIM, false><<<GEMM_MB, 512, 0, stream>>>(h1p, w2t, dinv, hn8);
  agg2_kernel<<<AGG_BLOCKS, 256, 0, stream>>>(hn8, dinv, rowptr, csr, b2, part);
  reduce2_kernel<<<RED_BLOCKS, 256, 0, stream>>>(part, p2);
  final_kernel<<<1, 256, 0, stream>>>(p2, Wfc, bfc, out);
}

// Round 9
// 280.925 us; speedup vs baseline: 1.0140x; 1.0021x over previous
//
#include <hip/hip_runtime.h>
#include <stdint.h>

#define AS1 __attribute__((address_space(1)))
#define AS3 __attribute__((address_space(3)))

typedef __bf16 bf16x8 __attribute__((ext_vector_type(8)));
typedef float  f32x4  __attribute__((ext_vector_type(4)));
typedef unsigned short u16x8 __attribute__((ext_vector_type(8)));

static constexpr int NODES  = 50000;
static constexpr int EDGES  = 800000;
static constexpr int INDIM  = 512;
static constexpr int HIDDIM = 256;
static constexpr int NB_SCAN = (NODES + 255) / 256;   // 196
static constexpr int AGG_BLOCKS = NODES / 4;          // 12500 (exact)
static constexpr int RED_BLOCKS = 64;
static constexpr int GEMM_MB256 = (NODES + 255) / 256; // 196 row-blocks (BM=256)

// ---------------- ws layout (bytes) ----------------
static constexpr size_t OFF_PART = 0;            // f32  [12500][256]
static constexpr size_t OFF_HN   = 51200000;     // fp8  [50000][256] pre-scaled h (both layers)
static constexpr size_t OFF_H1P  = 76800000;     // bf16 [50000][256] relu(layer1) output
static constexpr size_t OFF_W1T  = 102400000;    // bf16 [256][512]
static constexpr size_t OFF_W2T  = 102662144;    // bf16 [256][256]
static constexpr size_t OFF_DEG  = 102793216;    // i32 [50000]
static constexpr size_t OFF_FILL = 102993216;    // i32 [50000]
static constexpr size_t OFF_ROWP = 103193216;    // i32 [50001]
static constexpr size_t OFF_CSR  = 103393280;    // i32 [800000]
static constexpr size_t OFF_BSUM = 106593280;    // i32 [196]
static constexpr size_t OFF_BOFF = 106594304;    // i32 [256]
static constexpr size_t OFF_FLAG = 106595328;    // i32 (1 => edge_index is int64)
static constexpr size_t OFF_P2   = 106595840;    // f32 [64][256]
static constexpr size_t OFF_DINV = 106661376;    // f32 [50000]

__device__ __forceinline__ unsigned short f2bf(float f) {
  unsigned u = __builtin_bit_cast(unsigned, f);
  unsigned r = (u + 0x7FFFu + ((u >> 16) & 1u)) >> 16;   // RNE
  return (unsigned short)r;
}
__device__ __forceinline__ float bf2f(unsigned short u) {
  return __builtin_bit_cast(float, ((unsigned)u) << 16);
}
__device__ __forceinline__ unsigned char f2fp8(float f) {
  int p = __builtin_amdgcn_cvt_pk_fp8_f32(f, f, 0, false);   // OCP e4m3fn on gfx950
  return (unsigned char)(p & 0xff);
}
__device__ __forceinline__ void acc_fp8(float4& a, unsigned u) {
  a.x += __builtin_amdgcn_cvt_f32_fp8(u, 0);
  a.y += __builtin_amdgcn_cvt_f32_fp8(u, 1);
  a.z += __builtin_amdgcn_cvt_f32_fp8(u, 2);
  a.w += __builtin_amdgcn_cvt_f32_fp8(u, 3);
}
__device__ __forceinline__ void gload_lds16(const unsigned short* g, unsigned short* l) {
  __builtin_amdgcn_global_load_lds((const AS1 void*)g, (AS3 void*)l, 16, 0, 0);
}

// ---------------- edge dtype detect ----------------
__global__ void detect_kernel(const int* __restrict__ ei, int* __restrict__ flag) {
  int t = threadIdx.x;  // 64 threads
  unsigned long long b = __ballot(ei[2 * t + 1] == 0);
  if (t == 0) *flag = (b == 0xFFFFFFFFFFFFFFFFull) ? 1 : 0;
}

// ---------------- degree histogram ----------------
__global__ __launch_bounds__(256) void hist_kernel(const int* __restrict__ ei,
                                                   const int* __restrict__ flag,
                                                   int* __restrict__ deg) {
  int e = blockIdx.x * 256 + threadIdx.x;        // grid exact: 3125*256 = 800000
  int f = *flag;
  int d = f ? ei[2 * (EDGES + e)] : ei[EDGES + e];
  atomicAdd(&deg[d], 1);
}

// ---------------- scan (3 kernels) + dinv ----------------
__global__ __launch_bounds__(256) void scan1_kernel(const int* __restrict__ deg,
                                                    int* __restrict__ rowptr,
                                                    int* __restrict__ bsum,
                                                    float* __restrict__ dinv) {
  __shared__ int s[256];
  int t = threadIdx.x, i = blockIdx.x * 256 + t;
  int v = (i < NODES) ? deg[i] : 0;
  if (i < NODES) dinv[i] = rsqrtf((float)(v + 1));   // +1 self-loop
  s[t] = v; __syncthreads();
  for (int off = 1; off < 256; off <<= 1) {
    int x = (t >= off) ? s[t - off] : 0;
    __syncthreads(); s[t] += x; __syncthreads();
  }
  if (i < NODES) rowptr[i] = s[t] - v;               // block-local exclusive
  if (t == 255) bsum[blockIdx.x] = s[255];
}
__global__ __launch_bounds__(256) void scan2_kernel(const int* __restrict__ bsum,
                                                    int* __restrict__ boff,
                                                    int* __restrict__ rowptrN) {
  __shared__ int s[256];
  int t = threadIdx.x;
  int v = (t < NB_SCAN) ? bsum[t] : 0;
  s[t] = v; __syncthreads();
  for (int off = 1; off < 256; off <<= 1) {
    int x = (t >= off) ? s[t - off] : 0;
    __syncthreads(); s[t] += x; __syncthreads();
  }
  if (t < NB_SCAN) boff[t] = s[t] - v;
  if (t == 255) *rowptrN = s[255];
}
__global__ __launch_bounds__(256) void scan3_kernel(int* __restrict__ rowptr,
                                                    const int* __restrict__ boff) {
  int i = blockIdx.x * 256 + threadIdx.x;
  if (i < NODES) rowptr[i] += boff[blockIdx.x];
}

// ---------------- CSR fill ----------------
__global__ __launch_bounds__(256) void fill_kernel(const int* __restrict__ ei,
                                                   const int* __restrict__ flag,
                                                   const int* __restrict__ rowptr,
                                                   int* __restrict__ fill,
                                                   int* __restrict__ csr) {
  int e = blockIdx.x * 256 + threadIdx.x;
  int f = *flag;
  int s, d;
  if (f) { s = ei[2 * e]; d = ei[2 * (EDGES + e)]; }
  else   { s = ei[e];     d = ei[EDGES + e]; }
  int p = atomicAdd(&fill[d], 1);
  csr[rowptr[d] + p] = s;
}

// ---------------- weight transpose + bf16 ----------------
__global__ __launch_bounds__(256) void transw_kernel(const float* __restrict__ W1,
                                                     const float* __restrict__ W2,
                                                     unsigned short* __restrict__ W1T,
                                                     unsigned short* __restrict__ W2T) {
  int t = blockIdx.x * 256 + threadIdx.x;           // 768*256 = 196608 exact
  if (t < INDIM * HIDDIM) {
    int n = t >> 9, k = t & 511;                    // W1T[n][k] = W1[k][n]
    W1T[t] = f2bf(W1[k * HIDDIM + n]);
  } else {
    int u = t - INDIM * HIDDIM;
    int n = u >> 8, k = u & 255;
    W2T[u] = f2bf(W2[k * HIDDIM + n]);
  }
}

// ---------------- GEMM: BM=256 x BN=256, BK=32 dbuf, 512 thr / 8 waves ----
// 196 blocks (<= CU count): 1 block/CU, 16 step-slots total for K=512 (vs 49
// in R7) and minimal logical traffic (A read once = 102MB, B = 196 panels =
// 50MB). Wave tile 128x64 (2m x 4n), acc[8][4]. 64KB LDS double-buffered,
// XOR-swizzled; one barrier per K-step; fp32-A reg-staged (load early,
// cvt+write after MFMAs).
template<int K, bool AFP32>
__global__ __launch_bounds__(512, 2) void gemm_m256_kernel(const void* __restrict__ Av,
                                                           const unsigned short* __restrict__ BT,
                                                           const float* __restrict__ dinv,
                                                           unsigned char* __restrict__ Cn8) {
  constexpr int NSTEP = K / 32;
  __shared__ unsigned short As[2][256 * 32];   // 16 KB per buf
  __shared__ unsigned short Bs[2][256 * 32];   // 16 KB per buf (total 64 KB)
  const int tid = threadIdx.x, wave = tid >> 6, lane = tid & 63;
  const int fr = lane & 15, q = lane >> 4;
  const int wr = wave >> 2, wc = wave & 3;     // 2m x 4n
  const int m0 = blockIdx.x * 256;

  const int lrow4 = lane >> 2;                 // 0..15: row within 16-row slab
  const int sgq   = (lane & 3) ^ (lrow4 & 3);  // pre-swizzled source 16B group
  const unsigned short* a16 = (const unsigned short*)Av;
  const float*          a32 = (const float*)Av;

  f32x4 acc[8][4] = {};
  float4 fa[4];                                // fp32 A staging regs

  // B: 256 rows x 32 cols; wave covers 32 rows (2 slabs of 16).
#define STAGE_B(buf, kb)                                                      \
  {                                                                           \
    _Pragma("unroll")                                                         \
    for (int c = 0; c < 2; ++c) {                                             \
      int rbase = wave * 32 + c * 16;                                         \
      int gr = rbase + lrow4;                                                 \
      gload_lds16(BT + (size_t)gr * K + (kb) + sgq * 8, &Bs[buf][rbase * 32]);\
    }                                                                         \
  }
  // A bf16 (gemm2): identical geometry from a16 with row clamp.
#define STAGE_A16(buf, kb)                                                    \
  {                                                                           \
    _Pragma("unroll")                                                         \
    for (int c = 0; c < 2; ++c) {                                             \
      int rbase = wave * 32 + c * 16;                                         \
      int gr = m0 + rbase + lrow4; if (gr > NODES - 1) gr = NODES - 1;        \
      gload_lds16(a16 + (size_t)gr * K + (kb) + sgq * 8, &As[buf][rbase * 32]);\
    }                                                                         \
  }
  // A fp32: 256 rows x 8 float4 = 2048 chunks; 4/thread, lane-contiguous.
#define LOAD_A32(kb)                                                          \
  {                                                                           \
    _Pragma("unroll")                                                         \
    for (int j = 0; j < 4; ++j) {                                             \
      int F = tid + j * 512;                                                  \
      int r0 = m0 + (F >> 3); if (r0 > NODES - 1) r0 = NODES - 1;             \
      fa[j] = *(const float4*)(a32 + (size_t)r0 * K + (kb) + (F & 7) * 4);    \
    }                                                                         \
  }
#define WRITE_A32(buf)                                                        \
  {                                                                           \
    _Pragma("unroll")                                                         \
    for (int j = 0; j < 4; ++j) {                                             \
      int F = tid + j * 512;                                                  \
      int row = F >> 3, g4 = F & 7;                                           \
      ushort4 o{f2bf(fa[j].x), f2bf(fa[j].y), f2bf(fa[j].z), f2bf(fa[j].w)};  \
      int col = (((g4 >> 1) ^ (row & 3)) * 8) + (g4 & 1) * 4;                 \
      *(ushort4*)&As[buf][row * 32 + col] = o;                                \
    }                                                                         \
  }

  // ---- prologue: stage step 0 into buf 0 ----
  if constexpr (AFP32) { LOAD_A32(0); WRITE_A32(0); }
  else                 { STAGE_A16(0, 0); }
  STAGE_B(0, 0);
  __syncthreads();

  for (int t = 0; t < NSTEP; ++t) {
    const int cur = t & 1, nxt = cur ^ 1;
    const int kb1 = (t + 1) * 32;
    if (t + 1 < NSTEP) {                        // issue next-tile loads first
      if constexpr (AFP32) { LOAD_A32(kb1); }
      else                 { STAGE_A16(nxt, kb1); }
      STAGE_B(nxt, kb1);
    }
    bf16x8 af[8], bq[4];
#pragma unroll
    for (int m = 0; m < 8; ++m) {
      int row = wr * 128 + m * 16 + fr;
      af[m] = *(const bf16x8*)&As[cur][row * 32 + ((q ^ (row & 3)) * 8)];
    }
#pragma unroll
    for (int n = 0; n < 4; ++n) {
      int row = wc * 64 + n * 16 + fr;
      bq[n] = *(const bf16x8*)&Bs[cur][row * 32 + ((q ^ (row & 3)) * 8)];
    }
#pragma unroll
    for (int m = 0; m < 8; ++m)
#pragma unroll
      for (int n = 0; n < 4; ++n)
        acc[m][n] = __builtin_amdgcn_mfma_f32_16x16x32_bf16(af[m], bq[n], acc[m][n], 0, 0, 0);
    if (t + 1 < NSTEP) {
      if constexpr (AFP32) { WRITE_A32(nxt); }  // land A prefetch after MFMAs
    }
    __syncthreads();
  }
#undef STAGE_B
#undef STAGE_A16
#undef LOAD_A32
#undef WRITE_A32

  // epilogue: C/D layout col=lane&15, row=q*4+reg ; write fp8 with dinv scale
  const int rq = q * 4;
#pragma unroll
  for (int m = 0; m < 8; ++m) {
    int rbase = m0 + wr * 128 + m * 16 + rq;
#pragma unroll
    for (int r = 0; r < 4; ++r) {
      int grow = rbase + r;
      if (grow < NODES) {
        float dv = dinv[grow];
#pragma unroll
        for (int n = 0; n < 4; ++n) {
          int gcol = wc * 64 + n * 16 + fr;
          Cn8[(size_t)grow * 256 + gcol] = f2fp8(acc[m][n][r] * dv);
        }
      }
    }
  }
}

// ---------------- gather core: fp8 rows, unroll-8 (8 rows in flight) ----------------
__device__ __forceinline__ float4 gather_node(const unsigned char* __restrict__ hn8,
                                              const int* __restrict__ rowptr,
                                              const int* __restrict__ csr,
                                              int node, int boff) {
  float4 A{0.f, 0.f, 0.f, 0.f}, B{0.f, 0.f, 0.f, 0.f};
  unsigned us = *(const unsigned*)(hn8 + (size_t)node * 256 + boff);   // self-loop
  acc_fp8(A, us);
  int e0 = rowptr[node], e1 = rowptr[node + 1];
  int e = e0;
  for (; e + 8 <= e1; e += 8) {
    unsigned u0 = *(const unsigned*)(hn8 + (size_t)csr[e + 0] * 256 + boff);
    unsigned u1 = *(const unsigned*)(hn8 + (size_t)csr[e + 1] * 256 + boff);
    unsigned u2 = *(const unsigned*)(hn8 + (size_t)csr[e + 2] * 256 + boff);
    unsigned u3 = *(const unsigned*)(hn8 + (size_t)csr[e + 3] * 256 + boff);
    unsigned u4 = *(const unsigned*)(hn8 + (size_t)csr[e + 4] * 256 + boff);
    unsigned u5 = *(const unsigned*)(hn8 + (size_t)csr[e + 5] * 256 + boff);
    unsigned u6 = *(const unsigned*)(hn8 + (size_t)csr[e + 6] * 256 + boff);
    unsigned u7 = *(const unsigned*)(hn8 + (size_t)csr[e + 7] * 256 + boff);
    acc_fp8(A, u0); acc_fp8(B, u1); acc_fp8(A, u2); acc_fp8(B, u3);
    acc_fp8(A, u4); acc_fp8(B, u5); acc_fp8(A, u6); acc_fp8(B, u7);
  }
  for (; e + 4 <= e1; e += 4) {
    unsigned u0 = *(const unsigned*)(hn8 + (size_t)csr[e + 0] * 256 + boff);
    unsigned u1 = *(const unsigned*)(hn8 + (size_t)csr[e + 1] * 256 + boff);
    unsigned u2 = *(const unsigned*)(hn8 + (size_t)csr[e + 2] * 256 + boff);
    unsigned u3 = *(const unsigned*)(hn8 + (size_t)csr[e + 3] * 256 + boff);
    acc_fp8(A, u0); acc_fp8(B, u1); acc_fp8(A, u2); acc_fp8(B, u3);
  }
  for (; e < e1; ++e) {
    unsigned u = *(const unsigned*)(hn8 + (size_t)csr[e] * 256 + boff);
    acc_fp8(A, u);
  }
  return float4{A.x + B.x, A.y + B.y, A.z + B.z, A.w + B.w};
}

// ---------------- aggregation: wave per node, CSR gather ----------------
__global__ __launch_bounds__(256) void agg1_kernel(const unsigned char* __restrict__ hn8,
                                                   const float* __restrict__ dinv,
                                                   const int* __restrict__ rowptr,
                                                   const int* __restrict__ csr,
                                                   const float* __restrict__ bias,
                                                   unsigned short* __restrict__ outp) {
  int wave = threadIdx.x >> 6, lane = threadIdx.x & 63;
  int node = blockIdx.x * 4 + wave;
  int c0 = lane * 4;
  float4 a = gather_node(hn8, rowptr, csr, node, c0);
  float di = dinv[node];
  float4 b = *(const float4*)(bias + c0);
  ushort4 o{f2bf(fmaxf(fmaf(di, a.x, b.x), 0.f)),
            f2bf(fmaxf(fmaf(di, a.y, b.y), 0.f)),
            f2bf(fmaxf(fmaf(di, a.z, b.z), 0.f)),
            f2bf(fmaxf(fmaf(di, a.w, b.w), 0.f))};
  *(ushort4*)(outp + (size_t)node * 256 + c0) = o;
}

__global__ __launch_bounds__(256) void agg2_kernel(const unsigned char* __restrict__ hn8,
                                                   const float* __restrict__ dinv,
                                                   const int* __restrict__ rowptr,
                                                   const int* __restrict__ csr,
                                                   const float* __restrict__ bias,
                                                   float* __restrict__ partials) {
  __shared__ float sm[1024];
  int wave = threadIdx.x >> 6, lane = threadIdx.x & 63;
  int node = blockIdx.x * 4 + wave;                 // 12500*4 = 50000 exact
  int c0 = lane * 4;
  float4 a = gather_node(hn8, rowptr, csr, node, c0);
  float di = dinv[node];
  float4 b = *(const float4*)(bias + c0);
  sm[wave * 256 + c0 + 0] = fmaxf(fmaf(di, a.x, b.x), 0.f);
  sm[wave * 256 + c0 + 1] = fmaxf(fmaf(di, a.y, b.y), 0.f);
  sm[wave * 256 + c0 + 2] = fmaxf(fmaf(di, a.z, b.z), 0.f);
  sm[wave * 256 + c0 + 3] = fmaxf(fmaf(di, a.w, b.w), 0.f);
  __syncthreads();
  int t = threadIdx.x;
  partials[(size_t)blockIdx.x * 256 + t] = sm[t] + sm[256 + t] + sm[512 + t] + sm[768 + t];
}

// ---------------- readout ----------------
__global__ __launch_bounds__(256) void reduce2_kernel(const float* __restrict__ partials,
                                                      float* __restrict__ p2) {
  int t = threadIdx.x, b = blockIdx.x;              // 64 blocks
  float s = 0.f;
  for (int r = b; r < AGG_BLOCKS; r += RED_BLOCKS) s += partials[(size_t)r * 256 + t];
  p2[b * 256 + t] = s;
}
__global__ __launch_bounds__(256) void final_kernel(const float* __restrict__ p2,
                                                    const float* __restrict__ Wfc,
                                                    const float* __restrict__ bfc,
                                                    float* __restrict__ out) {
  __shared__ float red[256];
  int t = threadIdx.x;
  float s = 0.f;
  for (int b = 0; b < RED_BLOCKS; ++b) s += p2[b * 256 + t];
  float g = s * (1.0f / (float)NODES);
  red[t] = g * Wfc[t];
  __syncthreads();
  for (int off = 128; off > 0; off >>= 1) {
    if (t < off) red[t] += red[t + off];
    __syncthreads();
  }
  if (t == 0) {
    float z = red[0] + bfc[0];
    out[0] = 1.0f / (1.0f + expf(-z));
  }
}

// ---------------- launch ----------------
extern "C" void kernel_launch(void* const* d_in, const int* in_sizes, int n_in,
                              void* d_out, int out_size, void* d_ws, size_t ws_size,
                              hipStream_t stream) {
  (void)in_sizes; (void)n_in; (void)out_size; (void)ws_size;
  const float* x   = (const float*)d_in[0];
  const int*   ei  = (const int*)d_in[1];
  const float* W1  = (const float*)d_in[2];
  const float* b1  = (const float*)d_in[3];
  const float* W2  = (const float*)d_in[4];
  const float* b2  = (const float*)d_in[5];
  const float* Wfc = (const float*)d_in[6];
  const float* bfc = (const float*)d_in[7];
  float* out = (float*)d_out;
  char* ws = (char*)d_ws;

  unsigned char*  hn8  = (unsigned char*)(ws + OFF_HN);
  unsigned short* h1p  = (unsigned short*)(ws + OFF_H1P);
  unsigned short* w1t  = (unsigned short*)(ws + OFF_W1T);
  unsigned short* w2t  = (unsigned short*)(ws + OFF_W2T);
  int*   deg    = (int*)(ws + OFF_DEG);
  int*   fill   = (int*)(ws + OFF_FILL);
  int*   rowptr = (int*)(ws + OFF_ROWP);
  int*   csr    = (int*)(ws + OFF_CSR);
  int*   bsum   = (int*)(ws + OFF_BSUM);
  int*   boff   = (int*)(ws + OFF_BOFF);
  int*   flag   = (int*)(ws + OFF_FLAG);
  float* part   = (float*)(ws + OFF_PART);
  float* p2     = (float*)(ws + OFF_P2);
  float* dinv   = (float*)(ws + OFF_DINV);

  hipMemsetAsync(ws + OFF_DEG, 0, 400000, stream);  // deg + fill
  detect_kernel<<<1, 64, 0, stream>>>(ei, flag);
  hist_kernel<<<EDGES / 256, 256, 0, stream>>>(ei, flag, deg);
  scan1_kernel<<<NB_SCAN, 256, 0, stream>>>(deg, rowptr, bsum, dinv);
  scan2_kernel<<<1, 256, 0, stream>>>(bsum, boff, rowptr + NODES);
  scan3_kernel<<<NB_SCAN, 256, 0, stream>>>(rowptr, boff);
  fill_kernel<<<EDGES / 256, 256, 0, stream>>>(ei, flag, rowptr, fill, csr);

  transw_kernel<<<(INDIM * HIDDIM + HIDDIM * HIDDIM) / 256, 256, 0, stream>>>(W1, W2, w1t, w2t);

  gemm_m256_kernel<INDIM, true><<<GEMM_MB256, 512, 0, stream>>>(x, w1t, dinv, hn8);
  agg1_kernel<<<AGG_BLOCKS, 256, 0, stream>>>(hn8, dinv, rowptr, csr, b1, h1p);
  gemm_m256_kernel<HIDDIM, false><<<GEMM_MB256, 512, 0, stream>>>(h1p, w2t, dinv, hn8);
  agg2_kernel<<<AGG_BLOCKS, 256, 0, stream>>>(hn8, dinv, rowptr, csr, b2, part);
  reduce2_kernel<<<RED_BLOCKS, 256, 0, stream>>>(part, p2);
  final_kernel<<<1, 256, 0, stream>>>(p2, Wfc, bfc, out);
}

// Round 10
// 271.360 us; speedup vs baseline: 1.0497x; 1.0352x over previous
//
#include <hip/hip_runtime.h>
#include <stdint.h>

#define AS1 __attribute__((address_space(1)))
#define AS3 __attribute__((address_space(3)))

typedef __bf16 bf16x8 __attribute__((ext_vector_type(8)));
typedef float  f32x4  __attribute__((ext_vector_type(4)));
typedef unsigned short u16x8 __attribute__((ext_vector_type(8)));

static constexpr int NODES  = 50000;
static constexpr int EDGES  = 800000;
static constexpr int INDIM  = 512;
static constexpr int HIDDIM = 256;
static constexpr int NB_SCAN = (NODES + 255) / 256;   // 196
static constexpr int AGG_BLOCKS = NODES / 4;          // 12500 (exact)
static constexpr int RED_BLOCKS = 64;
static constexpr int GEMM_MB256 = (NODES + 255) / 256; // 196 row-blocks (BM=256)

// ---------------- ws layout (bytes) ----------------
static constexpr size_t OFF_PART = 0;            // f32  [12500][256]
static constexpr size_t OFF_HN   = 51200000;     // fp8  [50000][256] pre-scaled h (both layers)
static constexpr size_t OFF_H1P  = 76800000;     // bf16 [50000][256] relu(layer1) output
static constexpr size_t OFF_W1T  = 102400000;    // bf16 [256][512]
static constexpr size_t OFF_W2T  = 102662144;    // bf16 [256][256]
static constexpr size_t OFF_DEG  = 102793216;    // i32 [50000]
static constexpr size_t OFF_FILL = 102993216;    // i32 [50000]
static constexpr size_t OFF_ROWP = 103193216;    // i32 [50001]
static constexpr size_t OFF_CSR  = 103393280;    // i32 [800000]
static constexpr size_t OFF_BSUM = 106593280;    // i32 [196]
static constexpr size_t OFF_BOFF = 106594304;    // i32 [256]
static constexpr size_t OFF_P2   = 106595840;    // f32 [64][256]
static constexpr size_t OFF_DINV = 106661376;    // f32 [50000]

__device__ __forceinline__ unsigned short f2bf(float f) {
  unsigned u = __builtin_bit_cast(unsigned, f);
  unsigned r = (u + 0x7FFFu + ((u >> 16) & 1u)) >> 16;   // RNE
  return (unsigned short)r;
}
__device__ __forceinline__ float bf2f(unsigned short u) {
  return __builtin_bit_cast(float, ((unsigned)u) << 16);
}
__device__ __forceinline__ unsigned char f2fp8(float f) {
  int p = __builtin_amdgcn_cvt_pk_fp8_f32(f, f, 0, false);   // OCP e4m3fn on gfx950
  return (unsigned char)(p & 0xff);
}
__device__ __forceinline__ void acc_fp8(float4& a, unsigned u) {
  a.x += __builtin_amdgcn_cvt_f32_fp8(u, 0);
  a.y += __builtin_amdgcn_cvt_f32_fp8(u, 1);
  a.z += __builtin_amdgcn_cvt_f32_fp8(u, 2);
  a.w += __builtin_amdgcn_cvt_f32_fp8(u, 3);
}
__device__ __forceinline__ void gload_lds16(const unsigned short* g, unsigned short* l) {
  __builtin_amdgcn_global_load_lds((const AS1 void*)g, (AS3 void*)l, 16, 0, 0);
}

// counted-wait primitives (T4): raw barrier + literal-N vmcnt, compiler-fenced
#define WAITVM(N)  asm volatile("s_waitcnt vmcnt(" #N ")" ::: "memory")
#define WAITLGKM   asm volatile("s_waitcnt lgkmcnt(0)" ::: "memory")
#define HWBARRIER  { asm volatile("" ::: "memory"); __builtin_amdgcn_s_barrier(); \
                     asm volatile("" ::: "memory"); }

// ---------------- weight transpose + bf16 + scratch zeroing (fused) ----------------
__global__ __launch_bounds__(256) void transw_zero_kernel(const float* __restrict__ W1,
                                                          const float* __restrict__ W2,
                                                          unsigned short* __restrict__ W1T,
                                                          unsigned short* __restrict__ W2T,
                                                          int4* __restrict__ zreg) {
  int b = blockIdx.x, tid = threadIdx.x;
  if (b < 512) {                                    // W1T[n][k] = W1[k][n]
    int t = b * 256 + tid; int n = t >> 9, k = t & 511;
    W1T[t] = f2bf(W1[k * HIDDIM + n]);
  } else if (b < 768) {
    int u = (b - 512) * 256 + tid; int n = u >> 8, k = u & 255;
    W2T[u] = f2bf(W2[k * HIDDIM + n]);
  } else {                                          // zero deg+fill (400000 B)
    int i = (b - 768) * 256 + tid;
    if (i < 25000) zreg[i] = int4{0, 0, 0, 0};
  }
}

// ---------------- degree histogram (inline int64-layout detect) ----------------
__global__ __launch_bounds__(256) void hist_kernel(const int* __restrict__ ei,
                                                   int* __restrict__ deg) {
  __shared__ int sflag;
  if (threadIdx.x < 64) {
    unsigned long long b = __ballot(ei[2 * threadIdx.x + 1] == 0);
    if (threadIdx.x == 0) sflag = (b == 0xFFFFFFFFFFFFFFFFull) ? 1 : 0;
  }
  __syncthreads();
  int f = sflag;
  int e = blockIdx.x * 256 + threadIdx.x;        // grid exact: 3125*256 = 800000
  int d = f ? ei[2 * (EDGES + e)] : ei[EDGES + e];
  atomicAdd(&deg[d], 1);
}

// ---------------- scan (3 kernels) + dinv ----------------
__global__ __launch_bounds__(256) void scan1_kernel(const int* __restrict__ deg,
                                                    int* __restrict__ rowptr,
                                                    int* __restrict__ bsum,
                                                    float* __restrict__ dinv) {
  __shared__ int s[256];
  int t = threadIdx.x, i = blockIdx.x * 256 + t;
  int v = (i < NODES) ? deg[i] : 0;
  if (i < NODES) dinv[i] = rsqrtf((float)(v + 1));   // +1 self-loop
  s[t] = v; __syncthreads();
  for (int off = 1; off < 256; off <<= 1) {
    int x = (t >= off) ? s[t - off] : 0;
    __syncthreads(); s[t] += x; __syncthreads();
  }
  if (i < NODES) rowptr[i] = s[t] - v;               // block-local exclusive
  if (t == 255) bsum[blockIdx.x] = s[255];
}
__global__ __launch_bounds__(256) void scan2_kernel(const int* __restrict__ bsum,
                                                    int* __restrict__ boff,
                                                    int* __restrict__ rowptrN) {
  __shared__ int s[256];
  int t = threadIdx.x;
  int v = (t < NB_SCAN) ? bsum[t] : 0;
  s[t] = v; __syncthreads();
  for (int off = 1; off < 256; off <<= 1) {
    int x = (t >= off) ? s[t - off] : 0;
    __syncthreads(); s[t] += x; __syncthreads();
  }
  if (t < NB_SCAN) boff[t] = s[t] - v;
  if (t == 255) *rowptrN = s[255];
}
__global__ __launch_bounds__(256) void scan3_kernel(int* __restrict__ rowptr,
                                                    const int* __restrict__ boff) {
  int i = blockIdx.x * 256 + threadIdx.x;
  if (i < NODES) rowptr[i] += boff[blockIdx.x];
}

// ---------------- CSR fill (inline detect) ----------------
__global__ __launch_bounds__(256) void fill_kernel(const int* __restrict__ ei,
                                                   const int* __restrict__ rowptr,
                                                   int* __restrict__ fill,
                                                   int* __restrict__ csr) {
  __shared__ int sflag;
  if (threadIdx.x < 64) {
    unsigned long long b = __ballot(ei[2 * threadIdx.x + 1] == 0);
    if (threadIdx.x == 0) sflag = (b == 0xFFFFFFFFFFFFFFFFull) ? 1 : 0;
  }
  __syncthreads();
  int f = sflag;
  int e = blockIdx.x * 256 + threadIdx.x;
  int s, d;
  if (f) { s = ei[2 * e]; d = ei[2 * (EDGES + e)]; }
  else   { s = ei[e];     d = ei[EDGES + e]; }
  int p = atomicAdd(&fill[d], 1);
  csr[rowptr[d] + p] = s;
}

// ---------------- GEMM: BM=256 x BN=256, BK=32, counted-vmcnt pipeline (T3+T4) ----
// Raw s_barrier + literal vmcnt(N): next tile's loads stay in flight across the
// barriers (never drain to 0 mid-loop) -> continuous HBM stream instead of the
// per-step burst+drain that pinned R1-R9 at ~60us. Two barriers per K-step
// protect both LDS buffers. fp32-A path: loads early, cvt+ds_write after MFMAs,
// lgkmcnt(0) before bottom barrier.
template<int K, bool AFP32>
__global__ __launch_bounds__(512, 2) void gemm_m256_kernel(const void* __restrict__ Av,
                                                           const unsigned short* __restrict__ BT,
                                                           const float* __restrict__ dinv,
                                                           unsigned char* __restrict__ Cn8) {
  constexpr int NSTEP = K / 32;
  __shared__ unsigned short As[2][256 * 32];   // 16 KB per buf
  __shared__ unsigned short Bs[2][256 * 32];   // 16 KB per buf (total 64 KB)
  const int tid = threadIdx.x, wave = tid >> 6, lane = tid & 63;
  const int fr = lane & 15, q = lane >> 4;
  const int wr = wave >> 2, wc = wave & 3;     // 2m x 4n
  const int m0 = blockIdx.x * 256;

  const int lrow4 = lane >> 2;                 // 0..15: row within 16-row slab
  const int sgq   = (lane & 3) ^ (lrow4 & 3);  // pre-swizzled source 16B group
  const unsigned short* a16 = (const unsigned short*)Av;
  const float*          a32 = (const float*)Av;

  f32x4 acc[8][4] = {};
  float4 fa[4];                                // fp32 A staging regs

  // B: 256 rows x 32 cols; wave covers 32 rows (2 slabs of 16). 2 vm instr/wave.
#define STAGE_B(buf, kb)                                                      \
  {                                                                           \
    _Pragma("unroll")                                                         \
    for (int c = 0; c < 2; ++c) {                                             \
      int rbase = wave * 32 + c * 16;                                         \
      int gr = rbase + lrow4;                                                 \
      gload_lds16(BT + (size_t)gr * K + (kb) + sgq * 8, &Bs[buf][rbase * 32]);\
    }                                                                         \
  }
  // A bf16 (gemm2): identical geometry with row clamp. 2 vm instr/wave.
#define STAGE_A16(buf, kb)                                                    \
  {                                                                           \
    _Pragma("unroll")                                                         \
    for (int c = 0; c < 2; ++c) {                                             \
      int rbase = wave * 32 + c * 16;                                         \
      int gr = m0 + rbase + lrow4; if (gr > NODES - 1) gr = NODES - 1;        \
      gload_lds16(a16 + (size_t)gr * K + (kb) + sgq * 8, &As[buf][rbase * 32]);\
    }                                                                         \
  }
  // A fp32: 256 rows x 8 float4 = 2048 chunks; 4/thread, lane-contiguous. 4 vm.
#define LOAD_A32(kb)                                                          \
  {                                                                           \
    _Pragma("unroll")                                                         \
    for (int j = 0; j < 4; ++j) {                                             \
      int F = tid + j * 512;                                                  \
      int r0 = m0 + (F >> 3); if (r0 > NODES - 1) r0 = NODES - 1;             \
      fa[j] = *(const float4*)(a32 + (size_t)r0 * K + (kb) + (F & 7) * 4);    \
    }                                                                         \
  }
#define WRITE_A32(buf)                                                        \
  {                                                                           \
    _Pragma("unroll")                                                         \
    for (int j = 0; j < 4; ++j) {                                             \
      int F = tid + j * 512;                                                  \
      int row = F >> 3, g4 = F & 7;                                           \
      ushort4 o{f2bf(fa[j].x), f2bf(fa[j].y), f2bf(fa[j].z), f2bf(fa[j].w)};  \
      int col = (((g4 >> 1) ^ (row & 3)) * 8) + (g4 & 1) * 4;                 \
      *(ushort4*)&As[buf][row * 32 + col] = o;                                \
    }                                                                         \
  }

  // ---- prologue: tile 0 into buf 0; no barrier (iter-0 top barrier covers) ----
  if constexpr (AFP32) { LOAD_A32(0); WRITE_A32(0); WAITLGKM; }
  else                 { STAGE_A16(0, 0); }
  STAGE_B(0, 0);

  for (int t = 0; t < NSTEP; ++t) {
    const int cur = t & 1, nxt = cur ^ 1;
    if (t + 1 < NSTEP) {                        // issue next tile, then counted wait
      const int kb1 = (t + 1) * 32;
      if constexpr (AFP32) { LOAD_A32(kb1); } else { STAGE_A16(nxt, kb1); }
      STAGE_B(nxt, kb1);
      if constexpr (AFP32) { WAITVM(6); } else { WAITVM(4); }
    } else {
      WAITVM(0);
    }
    HWBARRIER;                                  // cur tile visible to all waves

    bf16x8 af[8], bq[4];
#pragma unroll
    for (int m = 0; m < 8; ++m) {
      int row = wr * 128 + m * 16 + fr;
      af[m] = *(const bf16x8*)&As[cur][row * 32 + ((q ^ (row & 3)) * 8)];
    }
#pragma unroll
    for (int n = 0; n < 4; ++n) {
      int row = wc * 64 + n * 16 + fr;
      bq[n] = *(const bf16x8*)&Bs[cur][row * 32 + ((q ^ (row & 3)) * 8)];
    }
#pragma unroll
    for (int m = 0; m < 8; ++m)
#pragma unroll
      for (int n = 0; n < 4; ++n)
        acc[m][n] = __builtin_amdgcn_mfma_f32_16x16x32_bf16(af[m], bq[n], acc[m][n], 0, 0, 0);

    if (t + 1 < NSTEP) {
      if constexpr (AFP32) { WRITE_A32(nxt); WAITLGKM; }   // land A after MFMAs
    }
    HWBARRIER;                                  // reads of cur done before reuse
  }
#undef STAGE_B
#undef STAGE_A16
#undef LOAD_A32
#undef WRITE_A32

  // epilogue: C/D layout col=lane&15, row=q*4+reg ; write fp8 with dinv scale
  const int rq = q * 4;
#pragma unroll
  for (int m = 0; m < 8; ++m) {
    int rbase = m0 + wr * 128 + m * 16 + rq;
#pragma unroll
    for (int r = 0; r < 4; ++r) {
      int grow = rbase + r;
      if (grow < NODES) {
        float dv = dinv[grow];
#pragma unroll
        for (int n = 0; n < 4; ++n) {
          int gcol = wc * 64 + n * 16 + fr;
          Cn8[(size_t)grow * 256 + gcol] = f2fp8(acc[m][n][r] * dv);
        }
      }
    }
  }
}

// ---------------- gather core: fp8 rows, unroll-8 (8 rows in flight) ----------------
__device__ __forceinline__ float4 gather_node(const unsigned char* __restrict__ hn8,
                                              const int* __restrict__ rowptr,
                                              const int* __restrict__ csr,
                                              int node, int boff) {
  float4 A{0.f, 0.f, 0.f, 0.f}, B{0.f, 0.f, 0.f, 0.f};
  unsigned us = *(const unsigned*)(hn8 + (size_t)node * 256 + boff);   // self-loop
  acc_fp8(A, us);
  int e0 = rowptr[node], e1 = rowptr[node + 1];
  int e = e0;
  for (; e + 8 <= e1; e += 8) {
    unsigned u0 = *(const unsigned*)(hn8 + (size_t)csr[e + 0] * 256 + boff);
    unsigned u1 = *(const unsigned*)(hn8 + (size_t)csr[e + 1] * 256 + boff);
    unsigned u2 = *(const unsigned*)(hn8 + (size_t)csr[e + 2] * 256 + boff);
    unsigned u3 = *(const unsigned*)(hn8 + (size_t)csr[e + 3] * 256 + boff);
    unsigned u4 = *(const unsigned*)(hn8 + (size_t)csr[e + 4] * 256 + boff);
    unsigned u5 = *(const unsigned*)(hn8 + (size_t)csr[e + 5] * 256 + boff);
    unsigned u6 = *(const unsigned*)(hn8 + (size_t)csr[e + 6] * 256 + boff);
    unsigned u7 = *(const unsigned*)(hn8 + (size_t)csr[e + 7] * 256 + boff);
    acc_fp8(A, u0); acc_fp8(B, u1); acc_fp8(A, u2); acc_fp8(B, u3);
    acc_fp8(A, u4); acc_fp8(B, u5); acc_fp8(A, u6); acc_fp8(B, u7);
  }
  for (; e + 4 <= e1; e += 4) {
    unsigned u0 = *(const unsigned*)(hn8 + (size_t)csr[e + 0] * 256 + boff);
    unsigned u1 = *(const unsigned*)(hn8 + (size_t)csr[e + 1] * 256 + boff);
    unsigned u2 = *(const unsigned*)(hn8 + (size_t)csr[e + 2] * 256 + boff);
    unsigned u3 = *(const unsigned*)(hn8 + (size_t)csr[e + 3] * 256 + boff);
    acc_fp8(A, u0); acc_fp8(B, u1); acc_fp8(A, u2); acc_fp8(B, u3);
  }
  for (; e < e1; ++e) {
    unsigned u = *(const unsigned*)(hn8 + (size_t)csr[e] * 256 + boff);
    acc_fp8(A, u);
  }
  return float4{A.x + B.x, A.y + B.y, A.z + B.z, A.w + B.w};
}

// ---------------- aggregation: wave per node, CSR gather ----------------
__global__ __launch_bounds__(256) void agg1_kernel(const unsigned char* __restrict__ hn8,
                                                   const float* __restrict__ dinv,
                                                   const int* __restrict__ rowptr,
                                                   const int* __restrict__ csr,
                                                   const float* __restrict__ bias,
                                                   unsigned short* __restrict__ outp) {
  int wave = threadIdx.x >> 6, lane = threadIdx.x & 63;
  int node = blockIdx.x * 4 + wave;
  int c0 = lane * 4;
  float4 a = gather_node(hn8, rowptr, csr, node, c0);
  float di = dinv[node];
  float4 b = *(const float4*)(bias + c0);
  ushort4 o{f2bf(fmaxf(fmaf(di, a.x, b.x), 0.f)),
            f2bf(fmaxf(fmaf(di, a.y, b.y), 0.f)),
            f2bf(fmaxf(fmaf(di, a.z, b.z), 0.f)),
            f2bf(fmaxf(fmaf(di, a.w, b.w), 0.f))};
  *(ushort4*)(outp + (size_t)node * 256 + c0) = o;
}

__global__ __launch_bounds__(256) void agg2_kernel(const unsigned char* __restrict__ hn8,
                                                   const float* __restrict__ dinv,
                                                   const int* __restrict__ rowptr,
                                                   const int* __restrict__ csr,
                                                   const float* __restrict__ bias,
                                                   float* __restrict__ partials) {
  __shared__ float sm[1024];
  int wave = threadIdx.x >> 6, lane = threadIdx.x & 63;
  int node = blockIdx.x * 4 + wave;                 // 12500*4 = 50000 exact
  int c0 = lane * 4;
  float4 a = gather_node(hn8, rowptr, csr, node, c0);
  float di = dinv[node];
  float4 b = *(const float4*)(bias + c0);
  sm[wave * 256 + c0 + 0] = fmaxf(fmaf(di, a.x, b.x), 0.f);
  sm[wave * 256 + c0 + 1] = fmaxf(fmaf(di, a.y, b.y), 0.f);
  sm[wave * 256 + c0 + 2] = fmaxf(fmaf(di, a.z, b.z), 0.f);
  sm[wave * 256 + c0 + 3] = fmaxf(fmaf(di, a.w, b.w), 0.f);
  __syncthreads();
  int t = threadIdx.x;
  partials[(size_t)blockIdx.x * 256 + t] = sm[t] + sm[256 + t] + sm[512 + t] + sm[768 + t];
}

// ---------------- readout ----------------
__global__ __launch_bounds__(256) void reduce2_kernel(const float* __restrict__ partials,
                                                      float* __restrict__ p2) {
  int t = threadIdx.x, b = blockIdx.x;              // 64 blocks
  float s = 0.f;
  for (int r = b; r < AGG_BLOCKS; r += RED_BLOCKS) s += partials[(size_t)r * 256 + t];
  p2[b * 256 + t] = s;
}
__global__ __launch_bounds__(256) void final_kernel(const float* __restrict__ p2,
                                                    const float* __restrict__ Wfc,
                                                    const float* __restrict__ bfc,
                                                    float* __restrict__ out) {
  __shared__ float red[256];
  int t = threadIdx.x;
  float s = 0.f;
  for (int b = 0; b < RED_BLOCKS; ++b) s += p2[b * 256 + t];
  float g = s * (1.0f / (float)NODES);
  red[t] = g * Wfc[t];
  __syncthreads();
  for (int off = 128; off > 0; off >>= 1) {
    if (t < off) red[t] += red[t + off];
    __syncthreads();
  }
  if (t == 0) {
    float z = red[0] + bfc[0];
    out[0] = 1.0f / (1.0f + expf(-z));
  }
}

// ---------------- launch ----------------
extern "C" void kernel_launch(void* const* d_in, const int* in_sizes, int n_in,
                              void* d_out, int out_size, void* d_ws, size_t ws_size,
                              hipStream_t stream) {
  (void)in_sizes; (void)n_in; (void)out_size; (void)ws_size;
  const float* x   = (const float*)d_in[0];
  const int*   ei  = (const int*)d_in[1];
  const float* W1  = (const float*)d_in[2];
  const float* b1  = (const float*)d_in[3];
  const float* W2  = (const float*)d_in[4];
  const float* b2  = (const float*)d_in[5];
  const float* Wfc = (const float*)d_in[6];
  const float* bfc = (const float*)d_in[7];
  float* out = (float*)d_out;
  char* ws = (char*)d_ws;

  unsigned char*  hn8  = (unsigned char*)(ws + OFF_HN);
  unsigned short* h1p  = (unsigned short*)(ws + OFF_H1P);
  unsigned short* w1t  = (unsigned short*)(ws + OFF_W1T);
  unsigned short* w2t  = (unsigned short*)(ws + OFF_W2T);
  int*   deg    = (int*)(ws + OFF_DEG);
  int*   fill   = (int*)(ws + OFF_FILL);
  int*   rowptr = (int*)(ws + OFF_ROWP);
  int*   csr    = (int*)(ws + OFF_CSR);
  int*   bsum   = (int*)(ws + OFF_BSUM);
  int*   boff   = (int*)(ws + OFF_BOFF);
  float* part   = (float*)(ws + OFF_PART);
  float* p2     = (float*)(ws + OFF_P2);
  float* dinv   = (float*)(ws + OFF_DINV);

  transw_zero_kernel<<<866, 256, 0, stream>>>(W1, W2, w1t, w2t, (int4*)deg);
  hist_kernel<<<EDGES / 256, 256, 0, stream>>>(ei, deg);
  scan1_kernel<<<NB_SCAN, 256, 0, stream>>>(deg, rowptr, bsum, dinv);
  scan2_kernel<<<1, 256, 0, stream>>>(bsum, boff, rowptr + NODES);
  scan3_kernel<<<NB_SCAN, 256, 0, stream>>>(rowptr, boff);
  fill_kernel<<<EDGES / 256, 256, 0, stream>>>(ei, rowptr, fill, csr);

  gemm_m256_kernel<INDIM, true><<<GEMM_MB256, 512, 0, stream>>>(x, w1t, dinv, hn8);
  agg1_kernel<<<AGG_BLOCKS, 256, 0, stream>>>(hn8, dinv, rowptr, csr, b1, h1p);
  gemm_m256_kernel<HIDDIM, false><<<GEMM_MB256, 512, 0, stream>>>(h1p, w2t, dinv, hn8);
  agg2_kernel<<<AGG_BLOCKS, 256, 0, stream>>>(hn8, dinv, rowptr, csr, b2, part);
  reduce2_kernel<<<RED_BLOCKS, 256, 0, stream>>>(part, p2);
  final_kernel<<<1, 256, 0, stream>>>(p2, Wfc, bfc, out);
}